// Round 11
// baseline (194.958 us; speedup 1.0000x reference)
//
#include <hip/hip_runtime.h>
#include <hip/hip_bf16.h>

// ContrastiveLoss (SupCon-style), N=4096 rows, K=256 dim, TEMP=0.5.
// loss = mean over same-label off-diag pairs of [log(neg_i + e_ij) - t2_ij].
// e_ij <= e^2 ~ 7.4, neg_i >= ~550 -> log(neg_i+e) = log n + e/n (2nd-order
// dropped, <=1e-4 rel [R7]). Stats symmetric (e_ij = e_ji) -> per-COLUMN
// sums: exsum, pexp, pt2, pcnt; neg = exsum - pexp;
// loss = S_j [c log n + pe/n - tt] / S_j c.
//
// R11: R9/R10 proved the negsum interior is insensitive to staging/barriers/
// occupancy; remaining unaudited cost is INTER-DISPATCH: 3 graph nodes'
// launch/drain gaps + a lazy 16-block rowreduce (16 CUs active). Fuse the
// entire pipeline into ONE persistent kernel: 512 blocks x 256 thr,
// launch_bounds(256,2), 64KB LDS -> 2 blocks/CU co-resident guaranteed ->
// device-scope ticket grid-barriers are deadlock-free. Phases: (1) blocks
// 0-255 normalize+fp8-pack [R10 body]; (2) each block x2 blocktiles of the
// validated R10 negsum body; (3) all 512 blocks rowreduce (8 rows each),
// ticket finalize. Ctrl block zeroed by a 32B hipMemsetAsync node.
//
// pk8 layout per 16-row tile (4096 B):
//   byte[u*1024 + quad*256 + r16*16 + h*8 + j] = fp8(norm8[r16][quad*8+(2u+h)*32+j])
// -> chunk (tile,u) = 1KB = one gll16; lane's 16B = c-steps {2u,2u+1}.
// C/D: col = lane&15, row = (lane>>4)*4 + reg  [learn_hip m89/m91; R3-R10
// validated end-to-end]. x8 scaling; acc = 64*sim -> t2 = acc * 2^-5 exact.
//
// ws: [0,1MB) pk8; [2MB,6MB) part[4][64][4096] f32; [6MB,+32B) ctrl
//   (f[0]=loss, f[1]=cnt, i[2]=bar1, i[3]=bar2, i[4]=ticket).

#define N_ROWS 4096
#define K_DIM  256
#define GRID   512

typedef __attribute__((ext_vector_type(4))) float float4v;    // MFMA C/D
typedef __attribute__((ext_vector_type(4))) float f4;
typedef __attribute__((ext_vector_type(4))) int   int4v;
typedef __attribute__((ext_vector_type(2))) long  long2v;     // 2 x 8B frags

#define PK_OFF    0
#define PART_OFF  (2 * 1024 * 1024)
#define CTRL_OFF  (PART_OFF + 4 * 64 * N_ROWS * 4)     // +4 MB

// async global->LDS, 16B/lane: dest = wave-uniform base + lane*16 [m97 path]
__device__ __forceinline__ void gll16(const void* g, void* l) {
    __builtin_amdgcn_global_load_lds(
        (const __attribute__((address_space(1))) unsigned int*)g,
        (__attribute__((address_space(3))) unsigned int*)l, 16, 0, 0);
}

// device-scope grid barrier: release stores, arrive, spin, acquire.
__device__ __forceinline__ void gridbar(int* c) {
    __syncthreads();
    if (threadIdx.x == 0) {
        __threadfence();                       // release: flush this block's stores
        __hip_atomic_fetch_add(c, 1, __ATOMIC_ACQ_REL, __HIP_MEMORY_SCOPE_AGENT);
        while (__hip_atomic_load(c, __ATOMIC_ACQUIRE, __HIP_MEMORY_SCOPE_AGENT) < GRID)
            __builtin_amdgcn_s_sleep(2);
        __threadfence();                       // acquire: invalidate stale lines
    }
    __syncthreads();
}

// ---------------------------------------------------------------------------
__global__ __launch_bounds__(256, 2)
void fused_kernel(const float* __restrict__ emb,
                  const int* __restrict__ labels,
                  unsigned char* __restrict__ pk8,
                  float* __restrict__ part,
                  float* __restrict__ ctrl,
                  float* __restrict__ out) {
    __shared__ __align__(16) unsigned char smem[65536];
    int t = threadIdx.x;
    int w = t >> 6, lane = t & 63;
    int* ctrli = (int*)ctrl;

    // ================= Phase 1: normalize + fp8 pack (blocks 0-255) =======
    if (blockIdx.x < 256) {
        int tile = blockIdx.x;
        float* lds = (float*)smem;             // 16 KB
        float* sc  = (float*)(smem + 16384);   // 16 floats
        const f4* src = (const f4*)(emb + tile * 16 * 256);
        f4* dst4 = (f4*)lds;
        #pragma unroll
        for (int it = 0; it < 4; ++it) dst4[t + 256 * it] = src[t + 256 * it];
        __syncthreads();
        int row = w * 4 + (lane >> 4);         // 4 rows per wave
        float s = 0.f;
        #pragma unroll
        for (int m = 0; m < 16; ++m) {
            float x = lds[row * 256 + (lane & 15) + 16 * m];
            s += x * x;
        }
        s += __shfl_xor(s, 1); s += __shfl_xor(s, 2);
        s += __shfl_xor(s, 4); s += __shfl_xor(s, 8);
        float scale = 1.0f / fmaxf(sqrtf(s), 1e-12f);
        if ((lane & 15) == 0) sc[row] = scale;
        __syncthreads();
        int u = t >> 6, quad = (t >> 4) & 3, r16 = t & 15;
        float s8 = sc[r16] * 8.0f;
        const float* lr = lds + r16 * 256;
        int4v wv;
        #pragma unroll
        for (int wi = 0; wi < 4; ++wi) {
            int h  = wi >> 1;
            int j0 = (wi & 1) * 4;
            int kb = quad * 8 + (2 * u + h) * 32 + j0;
            float v0 = lr[kb + 0] * s8, v1 = lr[kb + 1] * s8;
            float v2 = lr[kb + 2] * s8, v3 = lr[kb + 3] * s8;
            int wd = __builtin_amdgcn_cvt_pk_fp8_f32(v0, v1, 0, 0);
            wd     = __builtin_amdgcn_cvt_pk_fp8_f32(v2, v3, wd, 1);
            wv[wi] = wd;
        }
        *(int4v*)(pk8 + tile * 4096 + t * 16) = wv;
    }

    gridbar(ctrli + 2);                        // pk8 visible device-wide

    // ================= Phase 2: fused sim/exp/stats (2 blocktiles) ========
    {
        unsigned char* As8 = smem;             // 32 KB
        unsigned char* Bs8 = smem + 32768;     // 32 KB
        int lane16 = lane & 15, quad = lane >> 4;
        int wi = w >> 1, wj = w & 1;
        const char* pkb = (const char*)pk8;

        for (int it2 = 0; it2 < 2; ++it2) {
            int bt = blockIdx.x + it2 * GRID;  // 0..1023
            int bi = bt >> 5, bj = bt & 31;
            int ibase = bi * 128 + wi * 64;
            int jbase = bj * 128 + wj * 64;
            int labi[16], labj[4];
            #pragma unroll
            for (int it = 0; it < 4; ++it)
                #pragma unroll
                for (int r = 0; r < 4; ++r)
                    labi[it * 4 + r] = labels[ibase + it * 16 + quad * 4 + r];
            #pragma unroll
            for (int jt = 0; jt < 4; ++jt)
                labj[jt] = labels[jbase + jt * 16 + lane16];

            __syncthreads();                   // LDS free from previous phase/iter
            {
                int isA   = (w < 2);
                int wloc  = isA ? w : (w - 2);
                int btile = isA ? bi : bj;
                unsigned char* panel = isA ? As8 : Bs8;
                #pragma unroll
                for (int u = 0; u < 16; ++u) { // 4 tiles x 4 chunks per wave
                    int tl = wloc * 4 + (u >> 2), cs = u & 3;
                    gll16(pkb + (((btile * 8 + tl) << 12) | (cs << 10)) + lane * 16,
                          panel + (((tl << 2) | cs) << 10));
                }
            }

            float4v acc[4][4];
            #pragma unroll
            for (int a = 0; a < 4; ++a)
                #pragma unroll
                for (int b = 0; b < 4; ++b)
                    acc[a][b] = (float4v){0.f, 0.f, 0.f, 0.f};

            __syncthreads();                   // single drain of all 64 loads

            #pragma unroll
            for (int cs = 0; cs < 4; ++cs) {
                long2v av[4], bv[4];
                #pragma unroll
                for (int it = 0; it < 4; ++it)
                    av[it] = *(const long2v*)(As8 + (((((wi * 4 + it) << 2) | cs) << 10)) + lane * 16);
                #pragma unroll
                for (int jt = 0; jt < 4; ++jt)
                    bv[jt] = *(const long2v*)(Bs8 + (((((wj * 4 + jt) << 2) | cs) << 10)) + lane * 16);
                #pragma unroll
                for (int h = 0; h < 2; ++h)
                    #pragma unroll
                    for (int it = 0; it < 4; ++it)
                        #pragma unroll
                        for (int jt = 0; jt < 4; ++jt)
                            acc[it][jt] = __builtin_amdgcn_mfma_f32_16x16x32_fp8_fp8(
                                av[it][h], bv[jt][h], acc[it][jt], 0, 0, 0);
            }

            // epilogue: per-column stats (== per-row by symmetry); acc = 64*sim
            float ex[4] = {0,0,0,0}, pe[4] = {0,0,0,0};
            float tt[4] = {0,0,0,0}, pc[4] = {0,0,0,0};
            #pragma unroll
            for (int it = 0; it < 4; ++it) {
                #pragma unroll
                for (int jt = 0; jt < 4; ++jt) {
                    int j = jbase + jt * 16 + lane16;
                    #pragma unroll
                    for (int r = 0; r < 4; ++r) {
                        int i = ibase + it * 16 + quad * 4 + r;
                        float t2 = acc[it][jt][r] * 0.03125f;
                        float e  = __expf(t2);
                        bool keep = (i != j);
                        bool same = (labi[it * 4 + r] == labj[jt]);
                        ex[jt] += keep ? e : 0.0f;
                        float m = (same && keep) ? 1.0f : 0.0f;
                        pe[jt] = fmaf(m, e,  pe[jt]);
                        tt[jt] = fmaf(m, t2, tt[jt]);
                        pc[jt] += m;
                    }
                }
            }
            int i64 = bi * 2 + wi;
            #pragma unroll
            for (int jt = 0; jt < 4; ++jt) {
                float v0 = ex[jt], v1 = pe[jt], v2 = tt[jt], v3 = pc[jt];
                v0 += __shfl_xor(v0, 16); v0 += __shfl_xor(v0, 32);
                v1 += __shfl_xor(v1, 16); v1 += __shfl_xor(v1, 32);
                v2 += __shfl_xor(v2, 16); v2 += __shfl_xor(v2, 32);
                v3 += __shfl_xor(v3, 16); v3 += __shfl_xor(v3, 32);
                if (quad == 0) {
                    int col = jbase + jt * 16 + lane16;
                    part[((0 * 64 + i64) << 12) + col] = v0;
                    part[((1 * 64 + i64) << 12) + col] = v1;
                    part[((2 * 64 + i64) << 12) + col] = v2;
                    part[((3 * 64 + i64) << 12) + col] = v3;
                }
            }
        }
    }

    gridbar(ctrli + 3);                        // part[] visible device-wide

    // ================= Phase 3: rowreduce (8 rows per block) ==============
    {
        int rl = t & 7;                        // local row 0..7
        int sl = t >> 3;                       // slice 0..31 (2 chunks each)
        int row = blockIdx.x * 8 + rl;
        float s[4];
        #pragma unroll
        for (int st = 0; st < 4; ++st) {
            int ch0 = sl * 2;
            s[st] = part[((st * 64 + ch0)     << 12) + row]
                  + part[((st * 64 + ch0 + 1) << 12) + row];
        }
        #pragma unroll
        for (int st = 0; st < 4; ++st) {       // reduce 8 slices within wave
            s[st] += __shfl_xor(s[st], 8);
            s[st] += __shfl_xor(s[st], 16);
            s[st] += __shfl_xor(s[st], 32);
        }
        float* red = (float*)smem;             // [wave][stat][row] = 4*4*8
        if (lane < 8) {
            #pragma unroll
            for (int st = 0; st < 4; ++st)
                red[(w * 4 + st) * 8 + lane] = s[st];
        }
        __syncthreads();
        if (t < 8) {
            float ex = red[0*8+t] + red[4*8+t] + red[8*8+t]  + red[12*8+t];
            float pe = red[1*8+t] + red[5*8+t] + red[9*8+t]  + red[13*8+t];
            float tt = red[2*8+t] + red[6*8+t] + red[10*8+t] + red[14*8+t];
            float pc = red[3*8+t] + red[7*8+t] + red[11*8+t] + red[15*8+t];
            float lsum = 0.f;
            if (pc > 0.f) {
                float n = ex - pe;
                lsum = pc * logf(n) + pe / n - tt;
            } else {
                pc = 0.f;
            }
            lsum += __shfl_xor(lsum, 1); pc += __shfl_xor(pc, 1);
            lsum += __shfl_xor(lsum, 2); pc += __shfl_xor(pc, 2);
            lsum += __shfl_xor(lsum, 4); pc += __shfl_xor(pc, 4);
            if (t == 0) {
                atomicAdd(&ctrl[0], lsum);
                atomicAdd(&ctrl[1], pc);
                __threadfence();
                int ticket = atomicAdd(ctrli + 4, 1);
                if (ticket == GRID - 1) {
                    float ls = atomicAdd(&ctrl[0], 0.0f);
                    float cs = atomicAdd(&ctrl[1], 0.0f);
                    out[0] = ls / cs;
                }
            }
        }
    }
}

// ---------------------------------------------------------------------------
extern "C" void kernel_launch(void* const* d_in, const int* in_sizes, int n_in,
                              void* d_out, int out_size, void* d_ws, size_t ws_size,
                              hipStream_t stream) {
    const float* emb    = (const float*)d_in[0];
    const int*   labels = (const int*)d_in[1];
    float* out = (float*)d_out;
    char*  ws  = (char*)d_ws;

    unsigned char* pk8  = (unsigned char*)(ws + PK_OFF);
    float*         part = (float*)(ws + PART_OFF);
    float*         ctrl = (float*)(ws + CTRL_OFF);

    hipMemsetAsync(ctrl, 0, 32, stream);       // zero loss/cnt/bar1/bar2/ticket
    fused_kernel<<<GRID, 256, 0, stream>>>(emb, labels, pk8, part, ctrl, out);
}

// Round 12
// 78.886 us; speedup vs baseline: 2.4714x; 2.4714x over previous
//
#include <hip/hip_runtime.h>
#include <hip/hip_bf16.h>

// ContrastiveLoss (SupCon-style), N=4096 rows, K=256 dim, TEMP=0.5.
// loss = mean over same-label off-diag pairs of [log(neg_i + e_ij) - t2_ij].
// e <= e^2 ~ 7.4, neg >= ~550 -> log(neg+e) = log n + e/n (2nd-order dropped,
// <=1e-4 rel [R7]). Stats symmetric (e_ij = e_ji) -> per-COLUMN sums:
// exsum, pexp, pt2, pcnt; neg = exsum - pexp;
// loss = S_j [c log n + pe/n - tt] / S_j c.
//
// R12 (R11 persistent fusion REVERTED: 512 same-address device-scope
// fetch_adds serialize ~200ns each -> ~50us per grid barrier). R11's clean
// counter gift: total hbm_bytes 5.3MB -> working set is fully L2/L3-resident;
// plateau is cache-latency/issue-bound. This round = R9/R10 best (81.3us) +
// shaves: (1) A-panel direct global->VGPR (overlapped with B's async gll16),
// LDS 64->32KB -> 3 blocks/CU (more cross-block overlap) and -16 ds_reads;
// (2) XCD swizzle: blocks sharing bi land on one XCD (A-panel L2-local);
// (3) rowreduce 16->128 blocks, slice-parallel, ticket finalize.
//
// pk8 layout per 16-row tile (4096 B):
//   byte[u*1024 + quad*256 + r16*16 + h*8 + j] = fp8(norm8[r16][quad*8+(2u+h)*32+j])
// -> chunk (tile,u) = 1KB = one gll16/dwordx4 row; lane's 16B = c-steps
// {2u,2u+1} (k_local = quad*8 + j).
// C/D: col = lane&15, row = (lane>>4)*4 + reg  [learn_hip m89/m91; R3-R11
// validated end-to-end]. x8 scaling; acc = 64*sim -> t2 = acc * 2^-5 exact.
//
// ws: [0,1MB) pk8; [2MB,6MB) part[4][64][4096] f32; [6MB,+16B) acc[4]
//   (acc[0]=loss, acc[1]=cnt, acc[2]=ticket, acc[3]=pad).

#define N_ROWS 4096
#define K_DIM  256

typedef __attribute__((ext_vector_type(4))) float float4v;    // MFMA C/D
typedef __attribute__((ext_vector_type(4))) float f4;
typedef __attribute__((ext_vector_type(4))) int   int4v;
typedef __attribute__((ext_vector_type(2))) long  long2v;     // 2 x 8B frags

#define PK_OFF    0
#define PART_OFF  (2 * 1024 * 1024)
#define ACC_OFF   (PART_OFF + 4 * 64 * N_ROWS * 4)     // +4 MB

// async global->LDS, 16B/lane: dest = wave-uniform base + lane*16 [m97 path]
__device__ __forceinline__ void gll16(const void* g, void* l) {
    __builtin_amdgcn_global_load_lds(
        (const __attribute__((address_space(1))) unsigned int*)g,
        (__attribute__((address_space(3))) unsigned int*)l, 16, 0, 0);
}

// ---------------------------------------------------------------------------
// K1: block = one 16-row tile. Coalesced float4 loads -> LDS, per-row norms
// via 16-lane shuffle groups, x8-scaled fp8 pack, 16B/thread coalesced store.
__global__ void normalize_kernel(const float* __restrict__ emb,
                                 unsigned char* __restrict__ pk8,
                                 float* __restrict__ acc) {
    int tile = blockIdx.x, t = threadIdx.x;
    __shared__ float lds[16 * 256];
    __shared__ float sc[16];
    const f4* src = (const f4*)(emb + tile * 16 * 256);
    f4* dst4 = (f4*)lds;
    #pragma unroll
    for (int it = 0; it < 4; ++it) dst4[t + 256 * it] = src[t + 256 * it];
    __syncthreads();
    int wave = t >> 6, lane = t & 63;
    int row = wave * 4 + (lane >> 4);          // 4 rows per wave
    float s = 0.f;
    #pragma unroll
    for (int m = 0; m < 16; ++m) {
        float x = lds[row * 256 + (lane & 15) + 16 * m];
        s += x * x;
    }
    s += __shfl_xor(s, 1); s += __shfl_xor(s, 2);
    s += __shfl_xor(s, 4); s += __shfl_xor(s, 8);
    float scale = 1.0f / fmaxf(sqrtf(s), 1e-12f);
    if ((lane & 15) == 0) sc[row] = scale;
    __syncthreads();
    // pack 16 bytes: fixed (u, quad, r16) per thread; h,j sweep the 16B
    int u = t >> 6, quad = (t >> 4) & 3, r16 = t & 15;
    float s8 = sc[r16] * 8.0f;
    const float* lr = lds + r16 * 256;
    int4v wv;
    #pragma unroll
    for (int wi = 0; wi < 4; ++wi) {           // word wi = bytes 4wi..4wi+3
        int h  = wi >> 1;
        int j0 = (wi & 1) * 4;
        int kb = quad * 8 + (2 * u + h) * 32 + j0;
        float v0 = lr[kb + 0] * s8, v1 = lr[kb + 1] * s8;
        float v2 = lr[kb + 2] * s8, v3 = lr[kb + 3] * s8;
        int wd = __builtin_amdgcn_cvt_pk_fp8_f32(v0, v1, 0, 0);
        wd     = __builtin_amdgcn_cvt_pk_fp8_f32(v2, v3, wd, 1);
        wv[wi] = wd;
    }
    *(int4v*)(pk8 + tile * 4096 + t * 16) = wv;
    if (tile == 0 && t < 4) acc[t] = 0.0f;     // loss, cnt, ticket, pad
}

// ---------------------------------------------------------------------------
// K2: fp8 fused sim/exp/stats. Grid 1024 (XCD-swizzled) = 32x32 blocktiles of
// 128x128; 4 waves in 2x2, each a 64x64 subtile (4x4 MFMA frags).
// B-panel (32KB) staged via gll16 (async); A-frags loaded straight to VGPRs
// (16 dwordx4/wave, in flight alongside the gll16s). ONE barrier, then
// 16 ds_read_b128 + 128 MFMA per wave. 32KB LDS -> 3 blocks/CU.
__global__ __launch_bounds__(256, 3)
void negsum_kernel(const unsigned char* __restrict__ pk8,
                   const int* __restrict__ labels,
                   float* __restrict__ part) {
    __shared__ __align__(16) unsigned char Bs8[32768];   // 8 tiles x 4 chunks
    int t = threadIdx.x;
    int w = t >> 6, lane = t & 63;
    int lane16 = lane & 15, quad = lane >> 4;
    // XCD swizzle: 4 consecutive bi per XCD (A-panel stays L2-local)
    int xcd = blockIdx.x & 7, local = blockIdx.x >> 3;   // local 0..127
    int bi = xcd * 4 + (local >> 5);                     // 0..31
    int bj = local & 31;
    int wi = w >> 1, wj = w & 1;

    int ibase = bi * 128 + wi * 64;
    int jbase = bj * 128 + wj * 64;
    const char* pkb = (const char*)pk8;        // tile16 = 4KB, chunk = 1KB

    // ---- B-panel: 32 chunks of 1KB via async gll16 (8 per wave) ----
    #pragma unroll
    for (int u = 0; u < 8; ++u) {
        int c8 = w * 8 + u, tl = c8 >> 2, cs = c8 & 3;
        gll16(pkb + (((bj * 8 + tl) << 12) | (cs << 10)) + lane * 16,
              Bs8 + (c8 << 10));
    }
    // ---- A-frags straight to VGPRs (4 it-tiles x 4 cs, 16B each) ----
    long2v av[4][4];
    #pragma unroll
    for (int it = 0; it < 4; ++it)
        #pragma unroll
        for (int cs = 0; cs < 4; ++cs)
            av[it][cs] = *(const long2v*)(pkb
                + (((bi * 8 + wi * 4 + it) << 12) | (cs << 10)) + lane * 16);

    int labi[16], labj[4];
    #pragma unroll
    for (int it = 0; it < 4; ++it)
        #pragma unroll
        for (int r = 0; r < 4; ++r)
            labi[it * 4 + r] = labels[ibase + it * 16 + quad * 4 + r];
    #pragma unroll
    for (int jt = 0; jt < 4; ++jt)
        labj[jt] = labels[jbase + jt * 16 + lane16];

    float4v acc[4][4];
    #pragma unroll
    for (int a = 0; a < 4; ++a)
        #pragma unroll
        for (int b = 0; b < 4; ++b)
            acc[a][b] = (float4v){0.f, 0.f, 0.f, 0.f};

    __syncthreads();                           // drains gll16s (and A loads)

    #pragma unroll
    for (int cs = 0; cs < 4; ++cs) {
        long2v bv[4];
        #pragma unroll
        for (int jt = 0; jt < 4; ++jt)
            bv[jt] = *(const long2v*)(Bs8
                     + (((((wj * 4 + jt) << 2) | cs) << 10)) + lane * 16);
        #pragma unroll
        for (int h = 0; h < 2; ++h)
            #pragma unroll
            for (int it = 0; it < 4; ++it)
                #pragma unroll
                for (int jt = 0; jt < 4; ++jt)
                    acc[it][jt] = __builtin_amdgcn_mfma_f32_16x16x32_fp8_fp8(
                        av[it][cs][h], bv[jt][h], acc[it][jt], 0, 0, 0);
    }

    // epilogue: per-column stats (== per-row by symmetry); acc = 64*sim
    float ex[4] = {0,0,0,0}, pe[4] = {0,0,0,0};
    float tt[4] = {0,0,0,0}, pc[4] = {0,0,0,0};
    #pragma unroll
    for (int it = 0; it < 4; ++it) {
        #pragma unroll
        for (int jt = 0; jt < 4; ++jt) {
            int j = jbase + jt * 16 + lane16;
            #pragma unroll
            for (int r = 0; r < 4; ++r) {
                int i = ibase + it * 16 + quad * 4 + r;
                float t2 = acc[it][jt][r] * 0.03125f;   // 2*sim, exact pow2
                float e  = __expf(t2);
                bool keep = (i != j);
                bool same = (labi[it * 4 + r] == labj[jt]);
                ex[jt] += keep ? e : 0.0f;
                float m = (same && keep) ? 1.0f : 0.0f;
                pe[jt] = fmaf(m, e,  pe[jt]);
                tt[jt] = fmaf(m, t2, tt[jt]);
                pc[jt] += m;
            }
        }
    }
    int i64 = bi * 2 + wi;                     // this wave's 64-row chunk
    #pragma unroll
    for (int jt = 0; jt < 4; ++jt) {
        float v0 = ex[jt], v1 = pe[jt], v2 = tt[jt], v3 = pc[jt];
        v0 += __shfl_xor(v0, 16); v0 += __shfl_xor(v0, 32);
        v1 += __shfl_xor(v1, 16); v1 += __shfl_xor(v1, 32);
        v2 += __shfl_xor(v2, 16); v2 += __shfl_xor(v2, 32);
        v3 += __shfl_xor(v3, 16); v3 += __shfl_xor(v3, 32);
        if (quad == 0) {
            int col = jbase + jt * 16 + lane16;
            part[((0 * 64 + i64) << 12) + col] = v0;
            part[((1 * 64 + i64) << 12) + col] = v1;
            part[((2 * 64 + i64) << 12) + col] = v2;
            part[((3 * 64 + i64) << 12) + col] = v3;
        }
    }
}

// ---------------------------------------------------------------------------
// K3: slice-parallel rowreduce. Grid 128 x 256: block = 32 rows; thread
// (rl = t>>3, sl = t&7) sums 8 chunks of row (blk*32+rl); shfl over sl,
// per-row closed form on sl==0 lanes, wave+block reduce, ticket finalize.
__global__ void rowreduce_kernel(const float* __restrict__ part,
                                 float* __restrict__ acc,
                                 float* __restrict__ out) {
    int t = threadIdx.x;
    int rl = t >> 3, sl = t & 7;
    int row = blockIdx.x * 32 + rl;
    float s[4];
    #pragma unroll
    for (int st = 0; st < 4; ++st) {
        float v = 0.f;
        #pragma unroll
        for (int c = 0; c < 8; ++c)
            v += part[((st * 64 + (sl * 8 + c)) << 12) + row];
        s[st] = v;
    }
    #pragma unroll
    for (int st = 0; st < 4; ++st) {           // reduce over the 8 slices
        s[st] += __shfl_xor(s[st], 1);
        s[st] += __shfl_xor(s[st], 2);
        s[st] += __shfl_xor(s[st], 4);
    }
    float lsum = 0.f, pcm = 0.f;
    if (sl == 0 && s[3] > 0.f) {
        float n = s[0] - s[1];                 // neg = exsum - pexp
        lsum = s[3] * logf(n) + s[1] / n - s[2];
        pcm  = s[3];
    }
    #pragma unroll
    for (int m = 1; m < 64; m <<= 1) {         // full-wave sum (masked lanes=0)
        lsum += __shfl_xor(lsum, m);
        pcm  += __shfl_xor(pcm,  m);
    }
    __shared__ float sl4[4], sc4[4];
    int wave = t >> 6, lane = t & 63;
    if (lane == 0) { sl4[wave] = lsum; sc4[wave] = pcm; }
    __syncthreads();
    if (t == 0) {
        atomicAdd(&acc[0], sl4[0] + sl4[1] + sl4[2] + sl4[3]);
        atomicAdd(&acc[1], sc4[0] + sc4[1] + sc4[2] + sc4[3]);
        __threadfence();
        int ticket = atomicAdd((int*)(acc + 2), 1);
        if (ticket == 127) {
            float ls = atomicAdd(&acc[0], 0.0f);
            float cs = atomicAdd(&acc[1], 0.0f);
            out[0] = ls / cs;
        }
    }
}

// ---------------------------------------------------------------------------
extern "C" void kernel_launch(void* const* d_in, const int* in_sizes, int n_in,
                              void* d_out, int out_size, void* d_ws, size_t ws_size,
                              hipStream_t stream) {
    const float* emb    = (const float*)d_in[0];
    const int*   labels = (const int*)d_in[1];
    float* out = (float*)d_out;
    char*  ws  = (char*)d_ws;

    unsigned char* pk8  = (unsigned char*)(ws + PK_OFF);
    float*         part = (float*)(ws + PART_OFF);
    float*         acc  = (float*)(ws + ACC_OFF);

    normalize_kernel<<<N_ROWS / 16, 256, 0, stream>>>(emb, pk8, acc);
    negsum_kernel<<<1024, 256, 0, stream>>>(pk8, labels, part);
    rowreduce_kernel<<<128, 256, 0, stream>>>(part, acc, out);
}